// Round 2
// baseline (3980.129 us; speedup 1.0000x reference)
//
#include <hip/hip_runtime.h>
#include <hip/hip_bf16.h>
#include <cstdint>

// ---------------------------------------------------------------------------
// SentenceEncoder, chunk-persistent LSTM edition (cooperative launch).
//
// Per chunk of 16 timesteps: gather_embed (bf16 Xc) -> xproj_gemm (Xb =
// Xc @ Wih^T for 16 steps) -> lstm_chunk (cooperative, 16 recurrence steps
// in ONE launch, Whh LDS-resident, C/HMAX in registers, per-row-group
// release/acquire barriers between steps).
//
// lstm_chunk grid = 256 = 4 row-groups (128 batch rows) x 64 col-tiles
// (64 gate-cols). Row-groups are fully independent (LSTM recurrence is
// batch-parallel); each rg syncs its own 64 blocks. Cooperative launch
// guarantees co-residency, so the barrier cannot deadlock; a bounded spin
// (~20 ms) turns any residual residency bug into a wrong answer, not a hang.
//
// Gate permutation p = (j>>4)<<6 | g<<4 | (j&15): within each 64-col group,
// MFMA output col c = g*16+l16 -> gate g of j-lane l16, so the cell update is
// fully register-local. Xb packs the 4 gates of a j contiguously (ushort4).
// ---------------------------------------------------------------------------

typedef __bf16 bf16x8 __attribute__((ext_vector_type(8)));
typedef float f32x4 __attribute__((ext_vector_type(4)));

__device__ __forceinline__ float sigm(float x) {
    return 1.0f / (1.0f + __expf(-x));
}
__device__ __forceinline__ float tanh_fast(float x) {
    x = fminf(15.0f, fmaxf(-15.0f, x));
    float e = __expf(2.0f * x);
    return (e - 1.0f) / (e + 1.0f);
}
__device__ __forceinline__ ushort f2bu(float f) {
    __hip_bfloat16 h = __float2bfloat16(f);
    return __builtin_bit_cast(unsigned short, h);
}
__device__ __forceinline__ float bu2f(ushort u) {
    return __uint_as_float(((unsigned)u) << 16);
}
__device__ __forceinline__ void gl_lds16(const void* g, void* l) {
    __builtin_amdgcn_global_load_lds(
        (const __attribute__((address_space(1))) unsigned int*)g,
        (__attribute__((address_space(3))) unsigned int*)l, 16, 0, 0);
}

// ---------------------------------------------------------------------------
// Kernel 1: weight prep. WcT[p][k] bf16; p permuted gate col:
//   g = (p>>4)&3,  j = ((p>>6)<<4) | (p&15),  original row r = g*1024 + j.
// k: 0..511 = input dims (W_ih), 512..1535 = hidden dims (W_hh).
// ---------------------------------------------------------------------------
__global__ void prep_weights(const float* __restrict__ Wih,
                             const float* __restrict__ Whh,
                             const float* __restrict__ bih,
                             const float* __restrict__ bhh,
                             __hip_bfloat16* __restrict__ WcT,
                             float* __restrict__ biasc) {
    int p = blockIdx.y;
    int k = blockIdx.x * blockDim.x + threadIdx.x;  // 0..1535
    int g = (p >> 4) & 3;
    int j = ((p >> 6) << 4) | (p & 15);
    int r = g * 1024 + j;
    float v = (k < 512) ? Wih[(size_t)r * 512 + k]
                        : Whh[(size_t)r * 1024 + (k - 512)];
    WcT[(size_t)p * 1536 + k] = __float2bfloat16(v);
    if (k == 0) biasc[p] = bih[r] + bhh[r];
}

// ---------------------------------------------------------------------------
// Kernel 2: per-chunk embedding gather -> Xc bf16 [16][512][512],
// local row rb = t_local*512 + b', b' = q:0..255, s:256..511.
// ---------------------------------------------------------------------------
__global__ void gather_embed(const int* __restrict__ q,
                             const int* __restrict__ s,
                             const float* __restrict__ emb,
                             ushort* __restrict__ Xc, int t0) {
    int rb = blockIdx.x;  // t_local*512 + b'
    int t = t0 + (rb >> 9);
    int b = rb & 511;
    int tok = (b < 256) ? q[b * 128 + t] : s[(b - 256) * 128 + t];
    const float2* src = (const float2*)(emb + (size_t)tok * 512);
    ushort2* dst = (ushort2*)(Xc + (size_t)rb * 512);
    float2 v = src[threadIdx.x];
    ushort2 o;
    o.x = f2bu(v.x);
    o.y = f2bu(v.y);
    dst[threadIdx.x] = o;
}

// ---------------------------------------------------------------------------
// Kernel 3: state init. c=0, hmax=-1e30, h0=0, barrier counters = 0.
// ---------------------------------------------------------------------------
__global__ void init_state(float* __restrict__ C, float* __restrict__ HMAX,
                           ushort* __restrict__ H0,
                           unsigned int* __restrict__ bar) {
    int i = blockIdx.x * 256 + threadIdx.x;
    C[i] = 0.0f;
    HMAX[i] = -1e30f;
    H0[i] = 0;
    if (i < 16) bar[i] = 0;
}

// ---------------------------------------------------------------------------
// Kernel 4: Xproj chunk GEMM. Xb[r][.] = Xc[r][:] @ WcT[:][0:512]^T,
// r in [0,8192) (16 timesteps x 512 batch), K=512.
// Tiles: 128x128 per block, BK=128 (4 iters), 4 waves of 64x64 (4x4 acc).
// Store packs gates: col = l16*4 + g holds gate g of j-lane l16 (ushort4).
// grid (32 nt, 64 mt), block 256, 2 blocks/CU.
// ---------------------------------------------------------------------------
__global__ __launch_bounds__(256, 2) void xproj_gemm(
    const ushort* __restrict__ X,    // [8192][512] bf16
    const ushort* __restrict__ WcT,  // [4096][1536] bf16
    ushort* __restrict__ Xb) {       // [8192][4096] bf16 (chunk)
    __shared__ __align__(16) ushort As[128 * 128];  // 32 KB, swizzled units
    __shared__ __align__(16) ushort Bs[128 * 128];  // 32 KB

    const int tid = threadIdx.x;
    const int n0 = blockIdx.x * 128;
    const int m0 = blockIdx.y * 128;
    const int lane = tid & 63;
    const int w = tid >> 6;
    const int quad = lane >> 4;
    const int l16 = lane & 15;
    const int wm = (w >> 1) * 64;
    const int wn = (w & 1) * 64;

    f32x4 acc[4][4] = {};

    for (int it = 0; it < 4; ++it) {
        const int k0 = it * 128;
        __syncthreads();  // previous iter's frag reads done
#pragma unroll
        for (int i = 0; i < 8; ++i) {
            int u = i * 256 + tid;          // unit index (16 B units)
            int r = u >> 4;                 // tile row 0..127
            int cs = (u & 15) ^ (r & 15);   // swizzled source col-unit
            gl_lds16(X + (size_t)(m0 + r) * 512 + k0 + cs * 8,
                     (ushort*)As + (size_t)u * 8);
            gl_lds16(WcT + (size_t)(n0 + r) * 1536 + k0 + cs * 8,
                     (ushort*)Bs + (size_t)u * 8);
        }
        __syncthreads();  // vmcnt(0) drain + barrier: LDS ready
#pragma unroll
        for (int kb = 0; kb < 4; ++kb) {
            bf16x8 af[4], bfr[4];
            const int vsel = (kb << 2) | quad;
#pragma unroll
            for (int mi = 0; mi < 4; ++mi)
                af[mi] = *(const bf16x8*)(As +
                    (((wm + mi * 16 + l16) << 4) + (vsel ^ l16)) * 8);
#pragma unroll
            for (int ni = 0; ni < 4; ++ni)
                bfr[ni] = *(const bf16x8*)(Bs +
                    (((wn + ni * 16 + l16) << 4) + (vsel ^ l16)) * 8);
#pragma unroll
            for (int mi = 0; mi < 4; ++mi)
#pragma unroll
                for (int ni = 0; ni < 4; ++ni)
                    acc[mi][ni] = __builtin_amdgcn_mfma_f32_16x16x32_bf16(
                        af[mi], bfr[ni], acc[mi][ni], 0, 0, 0);
        }
    }

    // store: lane holds gates ni=0..3 of j-lane l16 for row quad*4+rg
#pragma unroll
    for (int mi = 0; mi < 4; ++mi)
#pragma unroll
        for (int rg = 0; rg < 4; ++rg) {
            ushort4 v;
            v.x = f2bu(acc[mi][0][rg]);
            v.y = f2bu(acc[mi][1][rg]);
            v.z = f2bu(acc[mi][2][rg]);
            v.w = f2bu(acc[mi][3][rg]);
            *(ushort4*)&Xb[(size_t)(m0 + wm + mi * 16 + quad * 4 + rg) * 4096 +
                           (n0 + wn + l16 * 4)] = v;
        }
}

// ---------------------------------------------------------------------------
// Kernel 5: 16 fused LSTM steps (one chunk). COOPERATIVE LAUNCH, grid 256.
// ---------------------------------------------------------------------------
__global__ __launch_bounds__(256, 1) void lstm_chunk(
    const ushort* __restrict__ Xb,    // [8192][4096] bf16, gate-quad cols
    const ushort* __restrict__ WcT,   // [4096][1536] bf16
    const float* __restrict__ biasc,  // [4096]
    ushort* __restrict__ H0,          // [512][1024] bf16
    ushort* __restrict__ H1,          // [512][1024] bf16
    float* __restrict__ C,            // [512][1024]
    float* __restrict__ HMAX,         // [512][1024]
    unsigned int* __restrict__ bar,   // [16] row-group barrier counters
    int chunk) {
    __shared__ __align__(16) ushort Bs[64 * 1024];  // 128 KB resident Whh^T

    const int tid = threadIdx.x;
    const int bid = blockIdx.x;
    // XCD-aware block->tile map: consecutive bids round-robin XCDs (bid&7);
    // rg = xcd>>1 keeps each rg's H rows hot in 2 XCDs' L2. Mapping choice
    // only affects locality, never correctness.
    const int xcd = bid & 7;
    const int slot = bid >> 3;
    const int rg = xcd >> 1;                  // 0..3  (128 batch rows)
    const int ct = ((xcd & 1) << 5) | slot;   // 0..63 (16 hidden j's)
    const int m0 = rg * 128;
    const int n0 = ct * 64;
    const int lane = tid & 63;
    const int w = tid >> 6;
    const int quad = lane >> 4;
    const int l16 = lane & 15;

    // ---- stage resident Whh tile (linear LDS dest, pre-swizzled global
    // source). Row r (=gate col), 128 units of 8 bf16; global unit v lives at
    // lds unit r*128 + (v&0x70) + ((v&15)^(r&15)).
#pragma unroll
    for (int i = 0; i < 32; ++i) {
        int ulin = i * 256 + tid;
        int r = ulin >> 7;
        int v = (ulin & 0x70) | ((ulin & 15) ^ (r & 15));
        gl_lds16(WcT + (size_t)(n0 + r) * 1536 + 512 + v * 8,
                 (ushort*)Bs + (size_t)ulin * 8);
    }

    // bias for this lane's j: 4 gates
    float bgate[4];
#pragma unroll
    for (int g = 0; g < 4; ++g) bgate[g] = biasc[n0 + g * 16 + l16];

    // C/HMAX register state: thread owns rows m0+w*32+mi*16+quad*4+r4, j=jg
    const int jg = ct * 16 + l16;  // global hidden index
    float creg[2][4], hmx[2][4];
#pragma unroll
    for (int mi = 0; mi < 2; ++mi)
#pragma unroll
        for (int r4 = 0; r4 < 4; ++r4) {
            int row = m0 + w * 32 + mi * 16 + quad * 4 + r4;
            creg[mi][r4] = C[(size_t)row * 1024 + jg];
            hmx[mi][r4] = HMAX[(size_t)row * 1024 + jg];
        }

    // prologue: prefetch Xb gate-quads for tt=0
    ushort4 xq[2][4];
#pragma unroll
    for (int mi = 0; mi < 2; ++mi)
#pragma unroll
        for (int r4 = 0; r4 < 4; ++r4) {
            int row = m0 + w * 32 + mi * 16 + quad * 4 + r4;
            xq[mi][r4] =
                *(const ushort4*)(Xb + (size_t)row * 4096 + n0 + l16 * 4);
        }

    __syncthreads();  // vmcnt drain + barrier: Bs resident

    const ushort* hin = H0;  // chunk enters with latest h in H0
    ushort* hout = H1;

#pragma unroll 1
    for (int tt = 0; tt < 16; ++tt) {
        // ---- gates = Hin @ Whh^T : A from global (per-wave rows), B from
        // resident LDS. No staging, no inner barriers.
        f32x4 acc[2][4] = {};
        const ushort* arow =
            hin + (size_t)(m0 + w * 32 + l16) * 1024 + quad * 8;
#pragma unroll 8
        for (int kt = 0; kt < 32; ++kt) {  // K = 32*32
            bf16x8 af0 = *(const bf16x8*)(arow + kt * 32);
            bf16x8 af1 = *(const bf16x8*)(arow + 16 * 1024 + kt * 32);
            bf16x8 bq[4];
            const int v = kt * 4 + quad;
#pragma unroll
            for (int ni = 0; ni < 4; ++ni) {
                int r = ni * 16 + l16;
                int off = r * 128 + (v & 0x70) + ((v & 15) ^ l16);
                bq[ni] = *(const bf16x8*)((ushort*)Bs + (size_t)off * 8);
            }
#pragma unroll
            for (int ni = 0; ni < 4; ++ni) {
                acc[0][ni] = __builtin_amdgcn_mfma_f32_16x16x32_bf16(
                    af0, bq[ni], acc[0][ni], 0, 0, 0);
                acc[1][ni] = __builtin_amdgcn_mfma_f32_16x16x32_bf16(
                    af1, bq[ni], acc[1][ni], 0, 0, 0);
            }
        }

        // ---- register-local cell update: acc[mi][g][r4] = gate g of
        // (row, jg). PyTorch gate order i,f,g,o == g index 0..3.
#pragma unroll
        for (int mi = 0; mi < 2; ++mi)
#pragma unroll
            for (int r4 = 0; r4 < 4; ++r4) {
                float gi = acc[mi][0][r4] + bu2f(xq[mi][r4].x) + bgate[0];
                float gf = acc[mi][1][r4] + bu2f(xq[mi][r4].y) + bgate[1];
                float gg = acc[mi][2][r4] + bu2f(xq[mi][r4].z) + bgate[2];
                float go = acc[mi][3][r4] + bu2f(xq[mi][r4].w) + bgate[3];
                float iv = sigm(gi);
                float fv = sigm(gf);
                float gv = tanh_fast(gg);
                float ov = sigm(go);
                float cn = fv * creg[mi][r4] + iv * gv;
                float h = ov * tanh_fast(cn);
                creg[mi][r4] = cn;
                hmx[mi][r4] = fmaxf(hmx[mi][r4], h);
                int row = m0 + w * 32 + mi * 16 + quad * 4 + r4;
                hout[(size_t)row * 1024 + jg] = f2bu(h);
            }

        // ---- row-group barrier (64 blocks) with Xb prefetch overlapped.
        if (tt < 15) {
            __syncthreads();  // all hout stores drained (vmcnt0 before bar)
            if (tid == 0)
                __hip_atomic_fetch_add(&bar[rg], 1u, __ATOMIC_RELEASE,
                                       __HIP_MEMORY_SCOPE_AGENT);
            // prefetch next step's Xb gate-quads while the barrier fills
#pragma unroll
            for (int mi = 0; mi < 2; ++mi)
#pragma unroll
                for (int r4 = 0; r4 < 4; ++r4) {
                    int row =
                        (tt + 1) * 512 + m0 + w * 32 + mi * 16 + quad * 4 + r4;
                    xq[mi][r4] = *(const ushort4*)(Xb + (size_t)row * 4096 +
                                                   n0 + l16 * 4);
                }
            if (tid == 0) {
                unsigned target = 64u * (unsigned)(chunk * 15 + tt + 1);
                int guard = 0;
                while (__hip_atomic_load(&bar[rg], __ATOMIC_RELAXED,
                                         __HIP_MEMORY_SCOPE_AGENT) < target &&
                       guard < (1 << 18)) {  // ~20 ms bound: fail, don't hang
                    ++guard;
                    __builtin_amdgcn_s_sleep(2);
                }
            }
            __syncthreads();
            (void)__hip_atomic_load(&bar[rg], __ATOMIC_ACQUIRE,
                                    __HIP_MEMORY_SCOPE_AGENT);
            const ushort* tmp = hin;
            hin = hout;
            hout = (ushort*)tmp;
        }
    }

    // ---- persist C/HMAX for next chunk ----
#pragma unroll
    for (int mi = 0; mi < 2; ++mi)
#pragma unroll
        for (int r4 = 0; r4 < 4; ++r4) {
            int row = m0 + w * 32 + mi * 16 + quad * 4 + r4;
            C[(size_t)row * 1024 + jg] = creg[mi][r4];
            HMAX[(size_t)row * 1024 + jg] = hmx[mi][r4];
        }
}

// ---------------------------------------------------------------------------
// Kernel 6: final linear + sigmoid.
// ---------------------------------------------------------------------------
__global__ void final_out(const float* __restrict__ HMAX,
                          const float* __restrict__ Wl,
                          const float* __restrict__ bl,
                          float* __restrict__ out) {
    int b = blockIdx.x;
    int tid = threadIdx.x;
    float s0 = 0.0f, s1 = 0.0f;
    for (int j = tid; j < 1024; j += 256) {
        float hq = HMAX[(size_t)b * 1024 + j];
        float hs = HMAX[(size_t)(256 + b) * 1024 + j];
        s0 += hq * Wl[j] + hs * Wl[1024 + j];
        s1 += hq * Wl[2048 + j] + hs * Wl[3072 + j];
    }
    __shared__ float r0[256], r1[256];
    r0[tid] = s0;
    r1[tid] = s1;
    __syncthreads();
    for (int off = 128; off > 0; off >>= 1) {
        if (tid < off) {
            r0[tid] += r0[tid + off];
            r1[tid] += r1[tid + off];
        }
        __syncthreads();
    }
    if (tid == 0) {
        out[b * 2 + 0] = sigm(r0[0] + bl[0]);
        out[b * 2 + 1] = sigm(r1[0] + bl[1]);
    }
}

// ---------------------------------------------------------------------------
extern "C" void kernel_launch(void* const* d_in, const int* in_sizes, int n_in,
                              void* d_out, int out_size, void* d_ws,
                              size_t ws_size, hipStream_t stream) {
    const int* q = (const int*)d_in[0];
    const int* s = (const int*)d_in[1];
    const float* emb = (const float*)d_in[2];
    const float* Wih = (const float*)d_in[3];
    const float* Whh = (const float*)d_in[4];
    const float* bih = (const float*)d_in[5];
    const float* bhh = (const float*)d_in[6];
    const float* Wl = (const float*)d_in[7];
    const float* bl = (const float*)d_in[8];
    float* out = (float*)d_out;

    // workspace layout (bytes, 16B-aligned); total 94,388,288
    // (strictly inside the previously-validated 119,554,048 envelope)
    char* ws = (char*)d_ws;
    __hip_bfloat16* WcT = (__hip_bfloat16*)(ws + 0);      // 12,582,912
    float* biasc = (float*)(ws + 12582912);               //     16,384
    ushort* Xc = (ushort*)(ws + 12599296);                //  8,388,608
    ushort* Xb = (ushort*)(ws + 20987904);                // 67,108,864
    ushort* H0 = (ushort*)(ws + 88096768);                //  1,048,576
    ushort* H1 = (ushort*)(ws + 89145344);                //  1,048,576
    float* C = (float*)(ws + 90193920);                   //  2,097,152
    float* HMAX = (float*)(ws + 92291072);                //  2,097,152
    unsigned int* bar = (unsigned int*)(ws + 94388224);   //         64

    prep_weights<<<dim3(6, 4096), 256, 0, stream>>>(Wih, Whh, bih, bhh, WcT,
                                                    biasc);
    init_state<<<2048, 256, 0, stream>>>(C, HMAX, H0, bar);

    for (int c = 0; c < 8; ++c) {
        gather_embed<<<8192, 256, 0, stream>>>(q, s, emb, Xc, c * 16);
        xproj_gemm<<<dim3(32, 64), 256, 0, stream>>>(Xc, (const ushort*)WcT,
                                                     Xb);
        const ushort* XbA = Xb;
        const ushort* WcTA = (const ushort*)WcT;
        const float* biascA = biasc;
        ushort* H0A = H0;
        ushort* H1A = H1;
        float* CA = C;
        float* HMA = HMAX;
        unsigned int* barA = bar;
        int ck = c;
        void* args[] = {&XbA, &WcTA, &biascA, &H0A, &H1A,
                        &CA,  &HMA,  &barA,   &ck};
        hipLaunchCooperativeKernel(reinterpret_cast<const void*>(&lstm_chunk),
                                   dim3(256), dim3(256), args, 0, stream);
    }
    final_out<<<256, 256, 0, stream>>>(HMAX, Wl, bl, out);
}

// Round 7
// 3672.379 us; speedup vs baseline: 1.0838x; 1.0838x over previous
//
#include <hip/hip_runtime.h>
#include <hip/hip_bf16.h>
#include <cstdint>

// ---------------------------------------------------------------------------
// SentenceEncoder, chunk-persistent LSTM edition (cooperative launch).
//
// Per chunk of 16 timesteps: gather_embed (bf16 Xc) -> xproj_gemm (Xb =
// Xc @ Wih^T for 16 steps) -> lstm_chunk (cooperative, 16 recurrence steps
// in ONE launch, Whh LDS-resident, C/HMAX in registers, per-row-group
// barriers between steps).
//
// Coherence protocol: EXACTLY the round-1 harness-PROVEN recipe (absmax 0.0):
//   producer: plain H stores -> __syncthreads (drains vmcnt; stores in L2)
//   -> tid0 RELEASE atomic (s_waitcnt + buffer_wbl2 + op: H pushed to LLC
//   before flag visible).
//   consumer: relaxed poll -> __syncthreads -> ALL-thread ACQUIRE load
//   (buffer_inv: stale L1/L2 dropped) -> plain A loads read fresh LLC data.
// Rounds 3-6 all replaced parts of this with __hip_atomic_* H data paths and
// all failed identically -> those lowerings are not trusted; none are used.
//
// The one change vs round-1 (barrier COST, not mechanism): the 64 RELEASE
// fetch_adds per row-group serialized on ONE LLC address (~64 RMW round
// trips per step). Now each block RELEASE-*stores* a monotonic epoch to its
// PRIVATE slot (same per-block wbl2+store semantics, zero RMW contention);
// wave 0 polls all 64 slots in parallel (lane l watches slot l, one
// coalesced load per round, __all ballot). Bounded spin: fails visibly.
//
// lstm_chunk grid = 256 = 4 row-groups (128 batch rows) x 64 col-tiles
// (64 gate-cols). Row-groups are independent; each syncs its own 64 blocks.
//
// Gate permutation p = (j>>4)<<6 | g<<4 | (j&15): within each 64-col group,
// MFMA output col c = g*16+l16 -> gate g of j-lane l16, so the cell update is
// fully register-local. Xb packs the 4 gates of a j contiguously (ushort4).
// ---------------------------------------------------------------------------

typedef __bf16 bf16x8 __attribute__((ext_vector_type(8)));
typedef float f32x4 __attribute__((ext_vector_type(4)));

__device__ __forceinline__ float sigm(float x) {
    return 1.0f / (1.0f + __expf(-x));
}
__device__ __forceinline__ float tanh_fast(float x) {
    x = fminf(15.0f, fmaxf(-15.0f, x));
    float e = __expf(2.0f * x);
    return (e - 1.0f) / (e + 1.0f);
}
__device__ __forceinline__ ushort f2bu(float f) {
    __hip_bfloat16 h = __float2bfloat16(f);
    return __builtin_bit_cast(unsigned short, h);
}
__device__ __forceinline__ float bu2f(ushort u) {
    return __uint_as_float(((unsigned)u) << 16);
}
__device__ __forceinline__ void gl_lds16(const void* g, void* l) {
    __builtin_amdgcn_global_load_lds(
        (const __attribute__((address_space(1))) unsigned int*)g,
        (__attribute__((address_space(3))) unsigned int*)l, 16, 0, 0);
}

// ---------------------------------------------------------------------------
// Kernel 1: weight prep. WcT[p][k] bf16; p permuted gate col:
//   g = (p>>4)&3,  j = ((p>>6)<<4) | (p&15),  original row r = g*1024 + j.
// k: 0..511 = input dims (W_ih), 512..1535 = hidden dims (W_hh).
// ---------------------------------------------------------------------------
__global__ void prep_weights(const float* __restrict__ Wih,
                             const float* __restrict__ Whh,
                             const float* __restrict__ bih,
                             const float* __restrict__ bhh,
                             __hip_bfloat16* __restrict__ WcT,
                             float* __restrict__ biasc) {
    int p = blockIdx.y;
    int k = blockIdx.x * blockDim.x + threadIdx.x;  // 0..1535
    int g = (p >> 4) & 3;
    int j = ((p >> 6) << 4) | (p & 15);
    int r = g * 1024 + j;
    float v = (k < 512) ? Wih[(size_t)r * 512 + k]
                        : Whh[(size_t)r * 1024 + (k - 512)];
    WcT[(size_t)p * 1536 + k] = __float2bfloat16(v);
    if (k == 0) biasc[p] = bih[r] + bhh[r];
}

// ---------------------------------------------------------------------------
// Kernel 2: per-chunk embedding gather -> Xc bf16 [16][512][512],
// local row rb = t_local*512 + b', b' = q:0..255, s:256..511.
// ---------------------------------------------------------------------------
__global__ void gather_embed(const int* __restrict__ q,
                             const int* __restrict__ s,
                             const float* __restrict__ emb,
                             ushort* __restrict__ Xc, int t0) {
    int rb = blockIdx.x;  // t_local*512 + b'
    int t = t0 + (rb >> 9);
    int b = rb & 511;
    int tok = (b < 256) ? q[b * 128 + t] : s[(b - 256) * 128 + t];
    const float2* src = (const float2*)(emb + (size_t)tok * 512);
    ushort2* dst = (ushort2*)(Xc + (size_t)rb * 512);
    float2 v = src[threadIdx.x];
    ushort2 o;
    o.x = f2bu(v.x);
    o.y = f2bu(v.y);
    dst[threadIdx.x] = o;
}

// ---------------------------------------------------------------------------
// Kernel 3: state init. c=0, hmax=-1e30, h0=0, barrier slots = 0.
// ---------------------------------------------------------------------------
__global__ void init_state(float* __restrict__ C, float* __restrict__ HMAX,
                           ushort* __restrict__ H0,
                           unsigned int* __restrict__ bar) {
    int i = blockIdx.x * 256 + threadIdx.x;
    C[i] = 0.0f;
    HMAX[i] = -1e30f;
    H0[i] = 0;
    if (i < 256) bar[i] = 0;
}

// ---------------------------------------------------------------------------
// Kernel 4: Xproj chunk GEMM. Xb[r][.] = Xc[r][:] @ WcT[:][0:512]^T,
// r in [0,8192) (16 timesteps x 512 batch), K=512.
// Tiles: 128x128 per block, BK=128 (4 iters), 4 waves of 64x64 (4x4 acc).
// Store packs gates: col = l16*4 + g holds gate g of j-lane l16 (ushort4).
// grid (32 nt, 64 mt), block 256, 2 blocks/CU.
// ---------------------------------------------------------------------------
__global__ __launch_bounds__(256, 2) void xproj_gemm(
    const ushort* __restrict__ X,    // [8192][512] bf16
    const ushort* __restrict__ WcT,  // [4096][1536] bf16
    ushort* __restrict__ Xb) {       // [8192][4096] bf16 (chunk)
    __shared__ __align__(16) ushort As[128 * 128];  // 32 KB, swizzled units
    __shared__ __align__(16) ushort Bs[128 * 128];  // 32 KB

    const int tid = threadIdx.x;
    const int n0 = blockIdx.x * 128;
    const int m0 = blockIdx.y * 128;
    const int lane = tid & 63;
    const int w = tid >> 6;
    const int quad = lane >> 4;
    const int l16 = lane & 15;
    const int wm = (w >> 1) * 64;
    const int wn = (w & 1) * 64;

    f32x4 acc[4][4] = {};

    for (int it = 0; it < 4; ++it) {
        const int k0 = it * 128;
        __syncthreads();  // previous iter's frag reads done
#pragma unroll
        for (int i = 0; i < 8; ++i) {
            int u = i * 256 + tid;          // unit index (16 B units)
            int r = u >> 4;                 // tile row 0..127
            int cs = (u & 15) ^ (r & 15);   // swizzled source col-unit
            gl_lds16(X + (size_t)(m0 + r) * 512 + k0 + cs * 8,
                     (ushort*)As + (size_t)u * 8);
            gl_lds16(WcT + (size_t)(n0 + r) * 1536 + k0 + cs * 8,
                     (ushort*)Bs + (size_t)u * 8);
        }
        __syncthreads();  // vmcnt(0) drain + barrier: LDS ready
#pragma unroll
        for (int kb = 0; kb < 4; ++kb) {
            bf16x8 af[4], bfr[4];
            const int vsel = (kb << 2) | quad;
#pragma unroll
            for (int mi = 0; mi < 4; ++mi)
                af[mi] = *(const bf16x8*)(As +
                    (((wm + mi * 16 + l16) << 4) + (vsel ^ l16)) * 8);
#pragma unroll
            for (int ni = 0; ni < 4; ++ni)
                bfr[ni] = *(const bf16x8*)(Bs +
                    (((wn + ni * 16 + l16) << 4) + (vsel ^ l16)) * 8);
#pragma unroll
            for (int mi = 0; mi < 4; ++mi)
#pragma unroll
                for (int ni = 0; ni < 4; ++ni)
                    acc[mi][ni] = __builtin_amdgcn_mfma_f32_16x16x32_bf16(
                        af[mi], bfr[ni], acc[mi][ni], 0, 0, 0);
        }
    }

    // store: lane holds gates ni=0..3 of j-lane l16 for row quad*4+rg
#pragma unroll
    for (int mi = 0; mi < 4; ++mi)
#pragma unroll
        for (int rg = 0; rg < 4; ++rg) {
            ushort4 v;
            v.x = f2bu(acc[mi][0][rg]);
            v.y = f2bu(acc[mi][1][rg]);
            v.z = f2bu(acc[mi][2][rg]);
            v.w = f2bu(acc[mi][3][rg]);
            *(ushort4*)&Xb[(size_t)(m0 + wm + mi * 16 + quad * 4 + rg) * 4096 +
                           (n0 + wn + l16 * 4)] = v;
        }
}

// ---------------------------------------------------------------------------
// Kernel 5: 16 fused LSTM steps (one chunk). COOPERATIVE LAUNCH, grid 256.
// ---------------------------------------------------------------------------
__global__ __launch_bounds__(256, 1) void lstm_chunk(
    const ushort* __restrict__ Xb,    // [8192][4096] bf16, gate-quad cols
    const ushort* __restrict__ WcT,   // [4096][1536] bf16
    const float* __restrict__ biasc,  // [4096]
    ushort* __restrict__ H0,          // [512][1024] bf16
    ushort* __restrict__ H1,          // [512][1024] bf16
    float* __restrict__ C,            // [512][1024]
    float* __restrict__ HMAX,         // [512][1024]
    unsigned int* __restrict__ bar,   // [4][64] per-block epoch slots
    int chunk) {
    __shared__ __align__(16) ushort Bs[64 * 1024];  // 128 KB resident Whh^T

    const int tid = threadIdx.x;
    const int bid = blockIdx.x;
    // XCD-aware block->tile map: consecutive bids round-robin XCDs (bid&7);
    // rg = xcd>>1 keeps each rg's H rows hot in 2 XCDs' L2. Mapping choice
    // only affects locality, never correctness.
    const int xcd = bid & 7;
    const int slot = bid >> 3;
    const int rg = xcd >> 1;                  // 0..3  (128 batch rows)
    const int ct = ((xcd & 1) << 5) | slot;   // 0..63 (16 hidden j's)
    const int m0 = rg * 128;
    const int n0 = ct * 64;
    const int lane = tid & 63;
    const int w = tid >> 6;
    const int quad = lane >> 4;
    const int l16 = lane & 15;

    // ---- stage resident Whh tile (linear LDS dest, pre-swizzled global
    // source). Row r (=gate col), 128 units of 8 bf16; global unit v lives at
    // lds unit r*128 + (v&0x70) + ((v&15)^(r&15)).
#pragma unroll
    for (int i = 0; i < 32; ++i) {
        int ulin = i * 256 + tid;
        int r = ulin >> 7;
        int v = (ulin & 0x70) | ((ulin & 15) ^ (r & 15));
        gl_lds16(WcT + (size_t)(n0 + r) * 1536 + 512 + v * 8,
                 (ushort*)Bs + (size_t)ulin * 8);
    }

    // bias for this lane's j: 4 gates
    float bgate[4];
#pragma unroll
    for (int g = 0; g < 4; ++g) bgate[g] = biasc[n0 + g * 16 + l16];

    // C/HMAX register state: thread owns rows m0+w*32+mi*16+quad*4+r4, j=jg
    const int jg = ct * 16 + l16;  // global hidden index
    float creg[2][4], hmx[2][4];
#pragma unroll
    for (int mi = 0; mi < 2; ++mi)
#pragma unroll
        for (int r4 = 0; r4 < 4; ++r4) {
            int row = m0 + w * 32 + mi * 16 + quad * 4 + r4;
            creg[mi][r4] = C[(size_t)row * 1024 + jg];
            hmx[mi][r4] = HMAX[(size_t)row * 1024 + jg];
        }

    // prologue: prefetch Xb gate-quads for tt=0
    ushort4 xq[2][4];
#pragma unroll
    for (int mi = 0; mi < 2; ++mi)
#pragma unroll
        for (int r4 = 0; r4 < 4; ++r4) {
            int row = m0 + w * 32 + mi * 16 + quad * 4 + r4;
            xq[mi][r4] =
                *(const ushort4*)(Xb + (size_t)row * 4096 + n0 + l16 * 4);
        }

    __syncthreads();  // vmcnt drain + barrier: Bs resident

    const ushort* hin = H0;  // chunk enters with latest h in H0
    ushort* hout = H1;

#pragma unroll 1
    for (int tt = 0; tt < 16; ++tt) {
        // ---- gates = Hin @ Whh^T : A plain loads (fresh post-inv), B from
        // resident LDS. No staging, no inner barriers. (round-1 proven)
        f32x4 acc[2][4] = {};
        const ushort* arow =
            hin + (size_t)(m0 + w * 32 + l16) * 1024 + quad * 8;
#pragma unroll 8
        for (int kt = 0; kt < 32; ++kt) {  // K = 32*32
            bf16x8 af0 = *(const bf16x8*)(arow + kt * 32);
            bf16x8 af1 = *(const bf16x8*)(arow + 16 * 1024 + kt * 32);
            bf16x8 bq[4];
            const int v = kt * 4 + quad;
#pragma unroll
            for (int ni = 0; ni < 4; ++ni) {
                int r = ni * 16 + l16;
                int off = r * 128 + (v & 0x70) + ((v & 15) ^ l16);
                bq[ni] = *(const bf16x8*)((ushort*)Bs + (size_t)off * 8);
            }
#pragma unroll
            for (int ni = 0; ni < 4; ++ni) {
                acc[0][ni] = __builtin_amdgcn_mfma_f32_16x16x32_bf16(
                    af0, bq[ni], acc[0][ni], 0, 0, 0);
                acc[1][ni] = __builtin_amdgcn_mfma_f32_16x16x32_bf16(
                    af1, bq[ni], acc[1][ni], 0, 0, 0);
            }
        }

        // ---- register-local cell update: acc[mi][g][r4] = gate g of
        // (row, jg). PyTorch gate order i,f,g,o == g index 0..3.
        // Plain H stores (round-1 proven path).
#pragma unroll
        for (int mi = 0; mi < 2; ++mi)
#pragma unroll
            for (int r4 = 0; r4 < 4; ++r4) {
                float gi = acc[mi][0][r4] + bu2f(xq[mi][r4].x) + bgate[0];
                float gf = acc[mi][1][r4] + bu2f(xq[mi][r4].y) + bgate[1];
                float gg = acc[mi][2][r4] + bu2f(xq[mi][r4].z) + bgate[2];
                float go = acc[mi][3][r4] + bu2f(xq[mi][r4].w) + bgate[3];
                float iv = sigm(gi);
                float fv = sigm(gf);
                float gv = tanh_fast(gg);
                float ov = sigm(go);
                float cn = fv * creg[mi][r4] + iv * gv;
                float h = ov * tanh_fast(cn);
                creg[mi][r4] = cn;
                hmx[mi][r4] = fmaxf(hmx[mi][r4], h);
                int row = m0 + w * 32 + mi * 16 + quad * 4 + r4;
                hout[(size_t)row * 1024 + jg] = f2bu(h);
            }

        // ---- row-group barrier (64 blocks), fan-out edition.
        // Producer: syncthreads (H stores in L2) + tid0 RELEASE *store* of
        // the step epoch to this block's PRIVATE slot (same wbl2+store
        // semantics as round-1's RELEASE add, but no LLC RMW serialization).
        // Consumer: wave 0 polls all 64 slots in parallel (lane l watches
        // slot l), then syncthreads + ALL-thread ACQUIRE load (buffer_inv).
        if (tt < 15) {
            const unsigned epoch = (unsigned)(chunk * 15 + tt + 1);
            __syncthreads();
            if (tid == 0)
                __hip_atomic_store(&bar[rg * 64 + ct], epoch,
                                   __ATOMIC_RELEASE, __HIP_MEMORY_SCOPE_AGENT);
            // prefetch next step's Xb gate-quads while the barrier fills
#pragma unroll
            for (int mi = 0; mi < 2; ++mi)
#pragma unroll
                for (int r4 = 0; r4 < 4; ++r4) {
                    int row =
                        (tt + 1) * 512 + m0 + w * 32 + mi * 16 + quad * 4 + r4;
                    xq[mi][r4] = *(const ushort4*)(Xb + (size_t)row * 4096 +
                                                   n0 + l16 * 4);
                }
            if (w == 0) {  // wave 0: parallel poll, one slot per lane
                int guard = 0;
                bool done = false;
                while (!done && guard < (1 << 15)) {  // bounded: no hangs
                    unsigned v = __hip_atomic_load(&bar[rg * 64 + lane],
                                                   __ATOMIC_RELAXED,
                                                   __HIP_MEMORY_SCOPE_AGENT);
                    done = __all(v >= epoch);
                    ++guard;
                }
            }
            __syncthreads();
            (void)__hip_atomic_load(&bar[rg * 64 + ct], __ATOMIC_ACQUIRE,
                                    __HIP_MEMORY_SCOPE_AGENT);
            const ushort* tmp = hin;
            hin = hout;
            hout = (ushort*)tmp;
        }
    }

    // ---- persist C/HMAX for next chunk ----
#pragma unroll
    for (int mi = 0; mi < 2; ++mi)
#pragma unroll
        for (int r4 = 0; r4 < 4; ++r4) {
            int row = m0 + w * 32 + mi * 16 + quad * 4 + r4;
            C[(size_t)row * 1024 + jg] = creg[mi][r4];
            HMAX[(size_t)row * 1024 + jg] = hmx[mi][r4];
        }
}

// ---------------------------------------------------------------------------
// Kernel 6: final linear + sigmoid.
// ---------------------------------------------------------------------------
__global__ void final_out(const float* __restrict__ HMAX,
                          const float* __restrict__ Wl,
                          const float* __restrict__ bl,
                          float* __restrict__ out) {
    int b = blockIdx.x;
    int tid = threadIdx.x;
    float s0 = 0.0f, s1 = 0.0f;
    for (int j = tid; j < 1024; j += 256) {
        float hq = HMAX[(size_t)b * 1024 + j];
        float hs = HMAX[(size_t)(256 + b) * 1024 + j];
        s0 += hq * Wl[j] + hs * Wl[1024 + j];
        s1 += hq * Wl[2048 + j] + hs * Wl[3072 + j];
    }
    __shared__ float r0[256], r1[256];
    r0[tid] = s0;
    r1[tid] = s1;
    __syncthreads();
    for (int off = 128; off > 0; off >>= 1) {
        if (tid < off) {
            r0[tid] += r0[tid + off];
            r1[tid] += r1[tid + off];
        }
        __syncthreads();
    }
    if (tid == 0) {
        out[b * 2 + 0] = sigm(r0[0] + bl[0]);
        out[b * 2 + 1] = sigm(r1[0] + bl[1]);
    }
}

// ---------------------------------------------------------------------------
extern "C" void kernel_launch(void* const* d_in, const int* in_sizes, int n_in,
                              void* d_out, int out_size, void* d_ws,
                              size_t ws_size, hipStream_t stream) {
    const int* q = (const int*)d_in[0];
    const int* s = (const int*)d_in[1];
    const float* emb = (const float*)d_in[2];
    const float* Wih = (const float*)d_in[3];
    const float* Whh = (const float*)d_in[4];
    const float* bih = (const float*)d_in[5];
    const float* bhh = (const float*)d_in[6];
    const float* Wl = (const float*)d_in[7];
    const float* bl = (const float*)d_in[8];
    float* out = (float*)d_out;

    // workspace layout (bytes, 16B-aligned); total 94,389,248
    // (strictly inside the previously-validated 119,554,048 envelope)
    char* ws = (char*)d_ws;
    __hip_bfloat16* WcT = (__hip_bfloat16*)(ws + 0);      // 12,582,912
    float* biasc = (float*)(ws + 12582912);               //     16,384
    ushort* Xc = (ushort*)(ws + 12599296);                //  8,388,608
    ushort* Xb = (ushort*)(ws + 20987904);                // 67,108,864
    ushort* H0 = (ushort*)(ws + 88096768);                //  1,048,576
    ushort* H1 = (ushort*)(ws + 89145344);                //  1,048,576
    float* C = (float*)(ws + 90193920);                   //  2,097,152
    float* HMAX = (float*)(ws + 92291072);                //  2,097,152
    unsigned int* bar = (unsigned int*)(ws + 94388224);   //      1,024

    prep_weights<<<dim3(6, 4096), 256, 0, stream>>>(Wih, Whh, bih, bhh, WcT,
                                                    biasc);
    init_state<<<2048, 256, 0, stream>>>(C, HMAX, H0, bar);

    for (int c = 0; c < 8; ++c) {
        gather_embed<<<8192, 256, 0, stream>>>(q, s, emb, Xc, c * 16);
        xproj_gemm<<<dim3(32, 64), 256, 0, stream>>>(Xc, (const ushort*)WcT,
                                                     Xb);
        const ushort* XbA = Xb;
        const ushort* WcTA = (const ushort*)WcT;
        const float* biascA = biasc;
        ushort* H0A = H0;
        ushort* H1A = H1;
        float* CA = C;
        float* HMA = HMAX;
        unsigned int* barA = bar;
        int ck = c;
        void* args[] = {&XbA, &WcTA, &biascA, &H0A, &H1A,
                        &CA,  &HMA,  &barA,   &ck};
        hipLaunchCooperativeKernel(reinterpret_cast<const void*>(&lstm_chunk),
                                   dim3(256), dim3(256), args, 0, stream);
    }
    final_out<<<256, 256, 0, stream>>>(HMAX, Wl, bl, out);
}